// Round 6
// baseline (515.139 us; speedup 1.0000x reference)
//
#include <hip/hip_runtime.h>
#include <math.h>

#define BH    64
#define NSEQ  4096
#define DDIM  64
#define MDIM  266
#define MPAD  272
#define KTS   40                     // kT row stride in ushorts (bank-friendly)
#define RATIO 0.06131393394849658f   // 1/sqrt(266)
#define NORMF 0.35355339059327373f   // 64^-0.25
#define DIAGF 0.0625f                // 0.5 * 64^-0.5
#define EPSF  1e-4f

typedef __attribute__((ext_vector_type(8))) short bf16x8;
typedef __attribute__((ext_vector_type(4))) float f32x4;

__device__ __forceinline__ unsigned fenc(float f) {
  unsigned u = __float_as_uint(f);
  return (u & 0x80000000u) ? ~u : (u | 0x80000000u);
}
__device__ __forceinline__ float fdec(unsigned u) {
  return (u & 0x80000000u) ? __uint_as_float(u & 0x7fffffffu) : __uint_as_float(~u);
}

__device__ __forceinline__ void split1(float x, unsigned short& h, unsigned short& l) {
  unsigned ux = __float_as_uint(x);
  float hf = __uint_as_float(ux & 0xffff0000u);
  h = (unsigned short)(ux >> 16);
  l = (unsigned short)(__float_as_uint(x - hf) >> 16);
}

__device__ __forceinline__ void splitf(float4 a, float4 b, bf16x8& hi, bf16x8& lo) {
  float x[8] = {a.x, a.y, a.z, a.w, b.x, b.y, b.z, b.w};
#pragma unroll
  for (int e = 0; e < 8; ++e) {
    unsigned short h, l;
    split1(x[e], h, l);
    hi[e] = (short)h;
    lo[e] = (short)l;
  }
}

// split-precision GEMM accumulate: acc += hh + hl + lh  (ll term ~2^-16, dropped)
__device__ __forceinline__ f32x4 mfma3(bf16x8 ah, bf16x8 al, bf16x8 bh, bf16x8 bl, f32x4 acc) {
  acc = __builtin_amdgcn_mfma_f32_16x16x32_bf16(ah, bh, acc, 0, 0, 0);
  acc = __builtin_amdgcn_mfma_f32_16x16x32_bf16(ah, bl, acc, 0, 0, 0);
  acc = __builtin_amdgcn_mfma_f32_16x16x32_bf16(al, bh, acc, 0, 0, 0);
  return acc;
}

// ---------------------------------------------------------------------------
// P prep: proj [266][64] f32 -> phi/plo [272][64] bf16 planes (rows >=266 zero)
// ---------------------------------------------------------------------------
__global__ __launch_bounds__(256) void pprep_kernel(const float* __restrict__ proj,
                                                    short* __restrict__ phi,
                                                    short* __restrict__ plo) {
  int idx = blockIdx.x * 256 + threadIdx.x;
  if (idx >= MPAD * DDIM) return;
  int j = idx >> 6;
  float x = (j < MDIM) ? proj[idx] : 0.f;
  unsigned short h, l;
  split1(x, h, l);
  phi[idx] = (short)h;
  plo[idx] = (short)l;
}

// ---------------------------------------------------------------------------
// Kernel A: global max of k_dash = NORMF*(K.P^T), MFMA bf16x3.
// 512 blocks x 8 chunks of 64 rows; one atomic per block.
// ---------------------------------------------------------------------------
__global__ __launch_bounds__(256) void kmax_kernel(const float* __restrict__ k,
                                                   const short* __restrict__ phi,
                                                   const short* __restrict__ plo,
                                                   unsigned* __restrict__ kmax) {
  __shared__ float sK[64 * 76];
  __shared__ float wmax[4];
  const int tid = threadIdx.x;
  const int lane = tid & 63, wv = tid >> 6, lrow = lane & 15, lgrp = lane >> 4;

  float tmax = -1e30f;
  for (int it = 0; it < 8; ++it) {
    const int chunk = blockIdx.x * 8 + it;   // 0..4095
    const int bh = chunk >> 6, ch = chunk & 63;
    const float* kb = k + ((size_t)bh * NSEQ + (size_t)ch * 64) * DDIM;
    __syncthreads();
#pragma unroll
    for (int t = 0; t < 4; ++t) {
      int fid = tid + t * 256, r = fid >> 4, d4 = fid & 15;
      *(float4*)&sK[r * 76 + d4 * 4] = ((const float4*)kb)[fid];
    }
    __syncthreads();

    bf16x8 ahi[2], alo[2];
#pragma unroll
    for (int s = 0; s < 2; ++s) {
      const float* p = &sK[(wv * 16 + lrow) * 76 + s * 32 + lgrp * 8];
      splitf(*(const float4*)p, *(const float4*)(p + 4), ahi[s], alo[s]);
    }

#pragma unroll
    for (int jt = 0; jt < 17; ++jt) {
      f32x4 acc = {0.f, 0.f, 0.f, 0.f};
#pragma unroll
      for (int s = 0; s < 2; ++s) {
        const size_t bo = ((size_t)(jt * 16 + lrow)) * DDIM + s * 32 + lgrp * 8;
        acc = mfma3(ahi[s], alo[s], *(const bf16x8*)(phi + bo), *(const bf16x8*)(plo + bo), acc);
      }
      if (jt < 16 || lrow < 10) {
#pragma unroll
        for (int i = 0; i < 4; ++i) tmax = fmaxf(tmax, acc[i]);
      }
    }
  }
#pragma unroll
  for (int off = 32; off; off >>= 1) tmax = fmaxf(tmax, __shfl_xor(tmax, off));
  if (lane == 0) wmax[wv] = tmax;
  __syncthreads();
  if (tid == 0) {
    float m = fmaxf(fmaxf(wmax[0], wmax[1]), fmaxf(wmax[2], wmax[3]));
    atomicMax(kmax, fenc(m * NORMF));
  }
}

// dash helper: one 32n x 16j tile set -> k' into kT; returns partial colsum
__device__ __forceinline__ float dash_one(int jt, const bf16x8* ahi, const bf16x8* alo,
                                          const short* __restrict__ phi,
                                          const short* __restrict__ plo,
                                          const float* sDiag, float stab,
                                          unsigned short* kThi, unsigned short* kTlo,
                                          int lrow, int lgrp) {
  float kssum = 0.f;
  const int jg = jt * 16 + lrow;
#pragma unroll
  for (int m = 0; m < 2; ++m) {
    f32x4 d = {0.f, 0.f, 0.f, 0.f};
#pragma unroll
    for (int s = 0; s < 2; ++s) {
      const size_t bo = ((size_t)jg) * DDIM + s * 32 + lgrp * 8;
      d = mfma3(ahi[m * 2 + s], alo[m * 2 + s],
                *(const bf16x8*)(phi + bo), *(const bf16x8*)(plo + bo), d);
    }
    ushort4 h4, l4;
#pragma unroll
    for (int i = 0; i < 4; ++i) {
      const int nl = m * 16 + lgrp * 4 + i;
      float kd = d[i] * NORMF;
      float kp = (jg < MDIM) ? RATIO * (__expf(kd - sDiag[nl] - stab) + EPSF) : 0.f;
      kssum += kp;
      unsigned short h, l;
      split1(kp, h, l);
      ((unsigned short*)&h4)[i] = h;
      ((unsigned short*)&l4)[i] = l;
    }
    *(ushort4*)&kThi[(size_t)jg * KTS + m * 16 + lgrp * 4] = h4;
    *(ushort4*)&kTlo[(size_t)jg * KTS + m * 16 + lgrp * 4] = l4;
  }
  return kssum;
}

// ---------------------------------------------------------------------------
// Kernel B v2: 32-row tiles; full 272-col k' plane in LDS per tile; 4 barriers
// per tile; NO atomics -- each (bh,c8) block stores a private slice
// ctxp[c8][bh][272][64] (+ ksump) into d_out-as-scratch; reduce kernel sums.
// Dash: wave wv owns j-tiles {wv,4+wv,8+wv,12+wv} (+16 for wv0), all 32 n.
// Ctx:  wave wv owns e-cols wv*16..+15, all 272 j, MFMA k-dim = 32 n.
// ---------------------------------------------------------------------------
__global__ __launch_bounds__(256, 3) void ctx_kernel(const float* __restrict__ k,
                                                     const float* __restrict__ v,
                                                     const short* __restrict__ phi,
                                                     const short* __restrict__ plo,
                                                     const unsigned* __restrict__ kmaxp,
                                                     float* __restrict__ ctxp,
                                                     float* __restrict__ ksump) {
  __shared__ unsigned short kThi[MPAD * KTS];   // 21.76 KB; first 9.7 KB overlaid by sK
  __shared__ unsigned short kTlo[MPAD * KTS];   // 21.76 KB
  __shared__ float sV[32 * 68];                 // 8.7 KB
  __shared__ float sDiag[32];
  float* sK = (float*)kThi;                     // staging overlay, stride 76, 32 rows

  const int tid = threadIdx.x;
  const int lane = tid & 63, wv = tid >> 6, lrow = lane & 15, lgrp = lane >> 4;
  const int bh = blockIdx.x >> 3, c8 = blockIdx.x & 7;
  const float stab = fdec(*kmaxp);
  const float* kb = k + ((size_t)bh * NSEQ + (size_t)c8 * 512) * DDIM;
  const float* vb = v + ((size_t)bh * NSEQ + (size_t)c8 * 512) * DDIM;

  f32x4 acc[17];
#pragma unroll
  for (int jt = 0; jt < 17; ++jt) acc[jt] = (f32x4){0.f, 0.f, 0.f, 0.f};
  float ks[5] = {0.f, 0.f, 0.f, 0.f, 0.f};

  for (int rt = 0; rt < 16; ++rt) {
    // stage 32 rows of K (into kT overlay) and V; prev B4 guarantees free
#pragma unroll
    for (int t = 0; t < 2; ++t) {
      int fid = tid + t * 256, r = fid >> 4, d4 = fid & 15;   // 512 float4
      *(float4*)&sK[r * 76 + d4 * 4] = ((const float4*)(kb + (size_t)rt * 32 * DDIM))[fid];
      *(float4*)&sV[r * 68 + d4 * 4] = ((const float4*)(vb + (size_t)rt * 32 * DDIM))[fid];
    }
    __syncthreads();   // B1: staging visible
    if (tid < 32) {
      float s = 0.f;
      const float* row = &sK[tid * 76];
#pragma unroll
      for (int d = 0; d < 64; d += 4) {
        float4 x = *(const float4*)(row + d);
        s = fmaf(x.x, x.x, fmaf(x.y, x.y, fmaf(x.z, x.z, fmaf(x.w, x.w, s))));
      }
      sDiag[tid] = s * DIAGF;
    }
    // dash A-frags: K rows m*16+lrow, d-cols s*32+lgrp*8..+8
    bf16x8 ahi[4], alo[4];   // [m*2+s]
#pragma unroll
    for (int m = 0; m < 2; ++m)
#pragma unroll
      for (int s = 0; s < 2; ++s) {
        const float* p = &sK[(m * 16 + lrow) * 76 + s * 32 + lgrp * 8];
        splitf(*(const float4*)p, *(const float4*)(p + 4), ahi[m * 2 + s], alo[m * 2 + s]);
      }
    // ctx B-frags: V[n = lgrp*8+q][e = wv*16+lrow]
    bf16x8 vbh, vbl;
    {
      float tv[8];
#pragma unroll
      for (int q = 0; q < 8; ++q) tv[q] = sV[(lgrp * 8 + q) * 68 + wv * 16 + lrow];
      splitf(make_float4(tv[0], tv[1], tv[2], tv[3]),
             make_float4(tv[4], tv[5], tv[6], tv[7]), vbh, vbl);
    }
    __syncthreads();   // B2: sK/sV reads drained; sDiag visible; kT writes may begin

#pragma unroll
    for (int t = 0; t < 4; ++t)
      ks[t] += dash_one(t * 4 + wv, ahi, alo, phi, plo, sDiag, stab, kThi, kTlo, lrow, lgrp);
    if (wv == 0)
      ks[4] += dash_one(16, ahi, alo, phi, plo, sDiag, stab, kThi, kTlo, lrow, lgrp);
    __syncthreads();   // B3: full k' plane ready

#pragma unroll
    for (int jt = 0; jt < 17; ++jt) {
      bf16x8 ah = *(const bf16x8*)&kThi[(size_t)(jt * 16 + lrow) * KTS + lgrp * 8];
      bf16x8 al = *(const bf16x8*)&kTlo[(size_t)(jt * 16 + lrow) * KTS + lgrp * 8];
      acc[jt] = mfma3(ah, al, vbh, vbl, acc[jt]);
    }
    __syncthreads();   // B4: kT reads done before next stage overwrite
  }

  // ksum partials: reduce over lgrp (n-coverage), store per (jt, lrow)
  float* ksb = ksump + (size_t)(c8 * BH + bh) * MPAD;
#pragma unroll
  for (int t = 0; t < 4; ++t) {
    float s = ks[t];
    s += __shfl_xor(s, 16);
    s += __shfl_xor(s, 32);
    if (lgrp == 0) ksb[(t * 4 + wv) * 16 + lrow] = s;
  }
  if (wv == 0) {
    float s = ks[4];
    s += __shfl_xor(s, 16);
    s += __shfl_xor(s, 32);
    if (lgrp == 0) ksb[256 + lrow] = s;
  }
  // ctx slice: j = jt*16 + lgrp*4 + i, e = wv*16 + lrow
  float* cxb = ctxp + (size_t)(c8 * BH + bh) * MPAD * DDIM;
#pragma unroll
  for (int jt = 0; jt < 17; ++jt)
#pragma unroll
    for (int i = 0; i < 4; ++i)
      cxb[(size_t)(jt * 16 + lgrp * 4 + i) * DDIM + wv * 16 + lrow] = acc[jt][i];
}

// ---------------------------------------------------------------------------
// Reduce: ctx = sum_c8 ctxp[c8]; ksum = sum_c8 ksump[c8]
// ---------------------------------------------------------------------------
__global__ __launch_bounds__(256) void reduce_kernel(const float* __restrict__ ctxp,
                                                     const float* __restrict__ ksump,
                                                     float* __restrict__ ctx,
                                                     float* __restrict__ ksum) {
  const size_t SL = (size_t)BH * MPAD * DDIM;   // slice floats
  const int gid = blockIdx.x * 256 + threadIdx.x;
  if (gid < (int)(SL / 4)) {
    float4 s = make_float4(0.f, 0.f, 0.f, 0.f);
#pragma unroll
    for (int c = 0; c < 8; ++c) {
      float4 x = ((const float4*)ctxp)[c * (SL / 4) + gid];
      s.x += x.x; s.y += x.y; s.z += x.z; s.w += x.w;
    }
    ((float4*)ctx)[gid] = s;
  }
  if (gid < BH * MPAD) {
    float s = 0.f;
#pragma unroll
    for (int c = 0; c < 8; ++c) s += ksump[(size_t)c * BH * MPAD + gid];
    ksum[gid] = s;
  }
}

// ---------------------------------------------------------------------------
// Kernel C (all-MFMA): q_dash MFMA -> in-register max/exp/Dinv -> q'' bf16
// split qT in LDS -> GEMM2 MFMA. 64 rows/block.
// ---------------------------------------------------------------------------
__global__ __launch_bounds__(256, 2) void out_kernel(const float* __restrict__ q,
                                                     const short* __restrict__ phi,
                                                     const short* __restrict__ plo,
                                                     const float* __restrict__ ctx,
                                                     const float* __restrict__ ksum,
                                                     float* __restrict__ out) {
  __shared__ float buf[64 * 76];   // Q tile; reused as qT bf16 hi/lo [64][72]
  __shared__ float sCtx[64 * 68];
  __shared__ float sDiag[64];
  __shared__ float sKs[MPAD];
  unsigned short* qThi = (unsigned short*)buf;
  unsigned short* qTlo = qThi + 64 * 72;
  const int tid = threadIdx.x;
  const int lane = tid & 63, wv = tid >> 6, lrow = lane & 15, lgrp = lane >> 4;
  const int bh = blockIdx.x >> 6, rc = blockIdx.x & 63;
  const float* qb = q + ((size_t)bh * NSEQ + (size_t)rc * 64) * DDIM;

#pragma unroll
  for (int t = 0; t < 4; ++t) {
    int fid = tid + t * 256, r = fid >> 4, d4 = fid & 15;
    *(float4*)&buf[r * 76 + d4 * 4] = ((const float4*)qb)[fid];
  }
  for (int t = tid; t < MPAD; t += 256) sKs[t] = (t < MDIM) ? ksum[(size_t)bh * MPAD + t] : 0.f;
  __syncthreads();
  if (tid < 64) {
    float s = 0.f;
    const float* row = &buf[tid * 76];
#pragma unroll
    for (int d = 0; d < 64; d += 4) {
      float4 x = *(const float4*)(row + d);
      s = fmaf(x.x, x.x, fmaf(x.y, x.y, fmaf(x.z, x.z, fmaf(x.w, x.w, s))));
    }
    sDiag[tid] = s * DIAGF;
  }
  bf16x8 ahi[2], alo[2];
#pragma unroll
  for (int s = 0; s < 2; ++s) {
    const float* p = &buf[(wv * 16 + lrow) * 76 + s * 32 + lgrp * 8];
    splitf(*(const float4*)p, *(const float4*)(p + 4), ahi[s], alo[s]);
  }
  __syncthreads();   // sDiag ready, buf reads drained -> buf reusable

  f32x4 qd[17];
#pragma unroll
  for (int jt = 0; jt < 17; ++jt) {
    f32x4 a = {0.f, 0.f, 0.f, 0.f};
#pragma unroll
    for (int s = 0; s < 2; ++s) {
      const size_t bo = ((size_t)(jt * 16 + lrow)) * DDIM + s * 32 + lgrp * 8;
      a = mfma3(ahi[s], alo[s], *(const bf16x8*)(phi + bo), *(const bf16x8*)(plo + bo), a);
    }
#pragma unroll
    for (int i = 0; i < 4; ++i) qd[jt][i] = a[i] * NORMF;
  }

  // rows wv*16 + lgrp*4 + i; 16 lanes (lrow) share each row set
  float di[4];
#pragma unroll
  for (int i = 0; i < 4; ++i) {
    float m = -1e30f;
#pragma unroll
    for (int jt = 0; jt < 17; ++jt)
      if (jt < 16 || lrow < 10) m = fmaxf(m, qd[jt][i]);
    m = fmaxf(m, __shfl_xor(m, 1));
    m = fmaxf(m, __shfl_xor(m, 2));
    m = fmaxf(m, __shfl_xor(m, 4));
    m = fmaxf(m, __shfl_xor(m, 8));
    const float dg = sDiag[wv * 16 + lgrp * 4 + i];
    float s = 0.f;
#pragma unroll
    for (int jt = 0; jt < 17; ++jt) {
      const int jg = jt * 16 + lrow;
      float val = (jg < MDIM) ? RATIO * (__expf(qd[jt][i] - dg - m) + EPSF) : 0.f;
      qd[jt][i] = val;
      s = fmaf(val, sKs[jg], s);
    }
    s += __shfl_xor(s, 1);
    s += __shfl_xor(s, 2);
    s += __shfl_xor(s, 4);
    s += __shfl_xor(s, 8);
    di[i] = 1.0f / s;
  }

  f32x4 accO[4];
#pragma unroll
  for (int mt = 0; mt < 4; ++mt) accO[mt] = (f32x4){0.f, 0.f, 0.f, 0.f};

#pragma unroll
  for (int c = 0; c < 5; ++c) {
    const int nwr = (c < 4) ? 4 : 2;   // chunk 4: t=1 zero-fill (mask stale LDS)
    const int nks = (c < 4) ? 2 : 1;
    const int jn = (c < 4) ? 64 : 10;
#pragma unroll
    for (int t = 0; t < nwr; ++t) {
      const int jt = c * 4 + t;
#pragma unroll
      for (int i = 0; i < 4; ++i) {
        unsigned short h = 0, l = 0;
        if (jt < 17) split1(qd[jt][i] * di[i], h, l);
        qThi[(wv * 16 + lgrp * 4 + i) * 72 + t * 16 + lrow] = h;
        qTlo[(wv * 16 + lgrp * 4 + i) * 72 + t * 16 + lrow] = l;
      }
    }
#pragma unroll
    for (int t = 0; t < 4; ++t) {
      int fid = tid + t * 256, r = fid >> 4, e4 = fid & 15;
      if (r < jn)
        *(float4*)&sCtx[r * 68 + e4 * 4] =
            ((const float4*)(ctx + ((size_t)bh * MPAD + c * 64 + r) * DDIM))[e4];
    }
    __syncthreads();   // qT chunk + sCtx chunk ready
#pragma unroll
    for (int ks2 = 0; ks2 < nks; ++ks2) {
      float tv[8];
#pragma unroll
      for (int e = 0; e < 8; ++e)
        tv[e] = sCtx[(ks2 * 32 + lgrp * 8 + e) * 68 + wv * 16 + lrow];
      bf16x8 cbh, cbl;
      splitf(make_float4(tv[0], tv[1], tv[2], tv[3]),
             make_float4(tv[4], tv[5], tv[6], tv[7]), cbh, cbl);
#pragma unroll
      for (int mt = 0; mt < 4; ++mt) {
        bf16x8 ah = *(const bf16x8*)&qThi[(mt * 16 + lrow) * 72 + ks2 * 32 + lgrp * 8];
        bf16x8 al = *(const bf16x8*)&qTlo[(mt * 16 + lrow) * 72 + ks2 * 32 + lgrp * 8];
        accO[mt] = mfma3(ah, al, cbh, cbl, accO[mt]);
      }
    }
    __syncthreads();   // reads done before next chunk overwrites
  }

#pragma unroll
  for (int mt = 0; mt < 4; ++mt) {
#pragma unroll
    for (int i = 0; i < 4; ++i) {
      const int r = mt * 16 + lgrp * 4 + i;
      out[((size_t)bh * NSEQ + (size_t)rc * 64 + r) * DDIM + wv * 16 + lrow] = accO[mt][i];
    }
  }
}

extern "C" void kernel_launch(void* const* d_in, const int* in_sizes, int n_in,
                              void* d_out, int out_size, void* d_ws, size_t ws_size,
                              hipStream_t stream) {
  (void)in_sizes; (void)n_in; (void)out_size; (void)ws_size;
  const float* q = (const float*)d_in[0];
  const float* k = (const float*)d_in[1];
  const float* v = (const float*)d_in[2];
  const float* proj = (const float*)d_in[3];
  float* out = (float*)d_out;

  // d_ws layout: kmax | ctx | ksum | phi | plo   (~4.6 MB)
  unsigned* kmax = (unsigned*)d_ws;
  float* ctx = (float*)((char*)d_ws + 256);
  float* ksum = ctx + (size_t)BH * MPAD * DDIM;
  short* phi = (short*)(ksum + (size_t)BH * MPAD);
  short* plo = phi + (size_t)MPAD * DDIM;

  // d_out used as scratch for the 8 ctx/ksum slices (36.2 MB < 67 MB);
  // out_kernel fully overwrites d_out afterwards.
  const size_t SL = (size_t)BH * MPAD * DDIM;
  float* ctxp = (float*)d_out;
  float* ksump = ctxp + 8 * SL;

  hipMemsetAsync(d_ws, 0, 256, stream);   // kmax only
  pprep_kernel<<<dim3((MPAD * DDIM + 255) / 256), dim3(256), 0, stream>>>(proj, phi, plo);
  kmax_kernel<<<dim3(512), dim3(256), 0, stream>>>(k, phi, plo, kmax);
  ctx_kernel<<<dim3(BH * 8), dim3(256), 0, stream>>>(k, v, phi, plo, kmax, ctxp, ksump);
  reduce_kernel<<<dim3((unsigned)(SL / 4 / 256)), dim3(256), 0, stream>>>(ctxp, ksump, ctx, ksum);
  out_kernel<<<dim3(BH * 64), dim3(256), 0, stream>>>(q, phi, plo, ctx, ksum, out);
}

// Round 7
// 325.200 us; speedup vs baseline: 1.5841x; 1.5841x over previous
//
#include <hip/hip_runtime.h>
#include <math.h>

#define BH    64
#define NSEQ  4096
#define DDIM  64
#define MDIM  266
#define MPAD  272
#define KTS   40                     // kT row stride in ushorts
#define RATIO 0.06131393394849658f   // 1/sqrt(266)
#define NORMF 0.35355339059327373f   // 64^-0.25
#define DIAGF 0.0625f                // 0.5 * 64^-0.5
#define EPSF  1e-4f

typedef __attribute__((ext_vector_type(8))) short bf16x8;
typedef __attribute__((ext_vector_type(4))) float f32x4;

__device__ __forceinline__ unsigned fenc(float f) {
  unsigned u = __float_as_uint(f);
  return (u & 0x80000000u) ? ~u : (u | 0x80000000u);
}
__device__ __forceinline__ float fdec(unsigned u) {
  return (u & 0x80000000u) ? __uint_as_float(u & 0x7fffffffu) : __uint_as_float(~u);
}

__device__ __forceinline__ void split1(float x, unsigned short& h, unsigned short& l) {
  unsigned ux = __float_as_uint(x);
  float hf = __uint_as_float(ux & 0xffff0000u);
  h = (unsigned short)(ux >> 16);
  l = (unsigned short)(__float_as_uint(x - hf) >> 16);
}

__device__ __forceinline__ void splitf(float4 a, float4 b, bf16x8& hi, bf16x8& lo) {
  float x[8] = {a.x, a.y, a.z, a.w, b.x, b.y, b.z, b.w};
#pragma unroll
  for (int e = 0; e < 8; ++e) {
    unsigned short h, l;
    split1(x[e], h, l);
    hi[e] = (short)h;
    lo[e] = (short)l;
  }
}

// split-precision GEMM accumulate: acc += hh + hl + lh  (ll term ~2^-16, dropped)
__device__ __forceinline__ f32x4 mfma3(bf16x8 ah, bf16x8 al, bf16x8 bh, bf16x8 bl, f32x4 acc) {
  acc = __builtin_amdgcn_mfma_f32_16x16x32_bf16(ah, bh, acc, 0, 0, 0);
  acc = __builtin_amdgcn_mfma_f32_16x16x32_bf16(ah, bl, acc, 0, 0, 0);
  acc = __builtin_amdgcn_mfma_f32_16x16x32_bf16(al, bh, acc, 0, 0, 0);
  return acc;
}

// ---------------------------------------------------------------------------
// P prep: proj [266][64] f32 -> phi/plo [272][64] bf16 planes (rows >=266 zero)
// ---------------------------------------------------------------------------
__global__ __launch_bounds__(256) void pprep_kernel(const float* __restrict__ proj,
                                                    short* __restrict__ phi,
                                                    short* __restrict__ plo) {
  int idx = blockIdx.x * 256 + threadIdx.x;
  if (idx >= MPAD * DDIM) return;
  int j = idx >> 6;
  float x = (j < MDIM) ? proj[idx] : 0.f;
  unsigned short h, l;
  split1(x, h, l);
  phi[idx] = (short)h;
  plo[idx] = (short)l;
}

// ---------------------------------------------------------------------------
// Kernel A: global max of k_dash = NORMF*(K.P^T), MFMA bf16x3.
// 512 blocks x 8 chunks of 64 rows; one atomic per block.
// ---------------------------------------------------------------------------
__global__ __launch_bounds__(256) void kmax_kernel(const float* __restrict__ k,
                                                   const short* __restrict__ phi,
                                                   const short* __restrict__ plo,
                                                   unsigned* __restrict__ kmax) {
  __shared__ float sK[64 * 76];
  __shared__ float wmax[4];
  const int tid = threadIdx.x;
  const int lane = tid & 63, wv = tid >> 6, lrow = lane & 15, lgrp = lane >> 4;

  float tmax = -1e30f;
  for (int it = 0; it < 8; ++it) {
    const int chunk = blockIdx.x * 8 + it;   // 0..4095
    const int bh = chunk >> 6, ch = chunk & 63;
    const float* kb = k + ((size_t)bh * NSEQ + (size_t)ch * 64) * DDIM;
    __syncthreads();
#pragma unroll
    for (int t = 0; t < 4; ++t) {
      int fid = tid + t * 256, r = fid >> 4, d4 = fid & 15;
      *(float4*)&sK[r * 76 + d4 * 4] = ((const float4*)kb)[fid];
    }
    __syncthreads();

    bf16x8 ahi[2], alo[2];
#pragma unroll
    for (int s = 0; s < 2; ++s) {
      const float* p = &sK[(wv * 16 + lrow) * 76 + s * 32 + lgrp * 8];
      splitf(*(const float4*)p, *(const float4*)(p + 4), ahi[s], alo[s]);
    }

#pragma unroll
    for (int jt = 0; jt < 17; ++jt) {
      f32x4 acc = {0.f, 0.f, 0.f, 0.f};
#pragma unroll
      for (int s = 0; s < 2; ++s) {
        const size_t bo = ((size_t)(jt * 16 + lrow)) * DDIM + s * 32 + lgrp * 8;
        acc = mfma3(ahi[s], alo[s], *(const bf16x8*)(phi + bo), *(const bf16x8*)(plo + bo), acc);
      }
      if (jt < 16 || lrow < 10) {
#pragma unroll
        for (int i = 0; i < 4; ++i) tmax = fmaxf(tmax, acc[i]);
      }
    }
  }
#pragma unroll
  for (int off = 32; off; off >>= 1) tmax = fmaxf(tmax, __shfl_xor(tmax, off));
  if (lane == 0) wmax[wv] = tmax;
  __syncthreads();
  if (tid == 0) {
    float m = fmaxf(fmaxf(wmax[0], wmax[1]), fmaxf(wmax[2], wmax[3]));
    atomicMax(kmax, fenc(m * NORMF));
  }
}

// dash helper, P-fragments from REGISTERS (rt-invariant, hoisted)
__device__ __forceinline__ float dash_reg(int jt, const bf16x8* ahi, const bf16x8* alo,
                                          const bf16x8* ph, const bf16x8* pl,
                                          const float* sDiag, float stab,
                                          unsigned short* kThi, unsigned short* kTlo,
                                          int lrow, int lgrp) {
  float kssum = 0.f;
  const int jg = jt * 16 + lrow;
#pragma unroll
  for (int m = 0; m < 2; ++m) {
    f32x4 d = {0.f, 0.f, 0.f, 0.f};
#pragma unroll
    for (int s = 0; s < 2; ++s)
      d = mfma3(ahi[m * 2 + s], alo[m * 2 + s], ph[s], pl[s], d);
    ushort4 h4, l4;
#pragma unroll
    for (int i = 0; i < 4; ++i) {
      const int nl = m * 16 + lgrp * 4 + i;
      float kd = d[i] * NORMF;
      float kp = (jg < MDIM) ? RATIO * (__expf(kd - sDiag[nl] - stab) + EPSF) : 0.f;
      kssum += kp;
      unsigned short h, l;
      split1(kp, h, l);
      ((unsigned short*)&h4)[i] = h;
      ((unsigned short*)&l4)[i] = l;
    }
    *(ushort4*)&kThi[(size_t)jg * KTS + m * 16 + lgrp * 4] = h4;
    *(ushort4*)&kTlo[(size_t)jg * KTS + m * 16 + lgrp * 4] = l4;
  }
  return kssum;
}

// ---------------------------------------------------------------------------
// Kernel B v3: P-fragments hoisted to registers before the rt loop (they are
// rt-invariant; R6 re-fetched 70KB of P from global 16x/block -> L2 thrash,
// 399MB HBM FETCH, latency-bound dash). 32-row tiles, 4 barriers/tile,
// no atomics (private slices + reduce).
// ---------------------------------------------------------------------------
__global__ __launch_bounds__(256, 2) void ctx_kernel(const float* __restrict__ k,
                                                     const float* __restrict__ v,
                                                     const short* __restrict__ phi,
                                                     const short* __restrict__ plo,
                                                     const unsigned* __restrict__ kmaxp,
                                                     float* __restrict__ ctxp,
                                                     float* __restrict__ ksump) {
  __shared__ unsigned short kThi[MPAD * KTS];   // 21.76 KB; first 9.7 KB overlaid by sK
  __shared__ unsigned short kTlo[MPAD * KTS];   // 21.76 KB
  __shared__ float sV[32 * 68];                 // 8.7 KB
  __shared__ float sDiag[32];
  float* sK = (float*)kThi;                     // staging overlay, stride 76, 32 rows

  const int tid = threadIdx.x;
  const int lane = tid & 63, wv = tid >> 6, lrow = lane & 15, lgrp = lane >> 4;
  const int bh = blockIdx.x & 63, c8 = blockIdx.x >> 6;   // XCD-affinity: xcd = bh%8
  const float stab = fdec(*kmaxp);
  const float* kb = k + ((size_t)bh * NSEQ + (size_t)c8 * 512) * DDIM;
  const float* vb = v + ((size_t)bh * NSEQ + (size_t)c8 * 512) * DDIM;

  // hoisted P-fragments: wave wv covers jt {wv, 4+wv, 8+wv, 12+wv} (+16 for wv0)
  bf16x8 pfh[4][2], pfl[4][2];
#pragma unroll
  for (int t = 0; t < 4; ++t)
#pragma unroll
    for (int s = 0; s < 2; ++s) {
      const size_t bo = ((size_t)((t * 4 + wv) * 16 + lrow)) * DDIM + s * 32 + lgrp * 8;
      pfh[t][s] = *(const bf16x8*)(phi + bo);
      pfl[t][s] = *(const bf16x8*)(plo + bo);
    }
  bf16x8 pfh4[2], pfl4[2];
  if (wv == 0) {
#pragma unroll
    for (int s = 0; s < 2; ++s) {
      const size_t bo = ((size_t)(256 + lrow)) * DDIM + s * 32 + lgrp * 8;
      pfh4[s] = *(const bf16x8*)(phi + bo);
      pfl4[s] = *(const bf16x8*)(plo + bo);
    }
  }

  f32x4 acc[17];
#pragma unroll
  for (int jt = 0; jt < 17; ++jt) acc[jt] = (f32x4){0.f, 0.f, 0.f, 0.f};
  float ks[5] = {0.f, 0.f, 0.f, 0.f, 0.f};

  for (int rt = 0; rt < 16; ++rt) {
    // stage 32 rows of K (into kT overlay) and V; prev B4 guarantees free
#pragma unroll
    for (int t = 0; t < 2; ++t) {
      int fid = tid + t * 256, r = fid >> 4, d4 = fid & 15;   // 512 float4
      *(float4*)&sK[r * 76 + d4 * 4] = ((const float4*)(kb + (size_t)rt * 32 * DDIM))[fid];
      *(float4*)&sV[r * 68 + d4 * 4] = ((const float4*)(vb + (size_t)rt * 32 * DDIM))[fid];
    }
    __syncthreads();   // B1: staging visible
    if (tid < 32) {
      float s = 0.f;
      const float* row = &sK[tid * 76];
#pragma unroll
      for (int d = 0; d < 64; d += 4) {
        float4 x = *(const float4*)(row + d);
        s = fmaf(x.x, x.x, fmaf(x.y, x.y, fmaf(x.z, x.z, fmaf(x.w, x.w, s))));
      }
      sDiag[tid] = s * DIAGF;
    }
    // dash A-frags: K rows m*16+lrow, d-cols s*32+lgrp*8..+8
    bf16x8 ahi[4], alo[4];   // [m*2+s]
#pragma unroll
    for (int m = 0; m < 2; ++m)
#pragma unroll
      for (int s = 0; s < 2; ++s) {
        const float* p = &sK[(m * 16 + lrow) * 76 + s * 32 + lgrp * 8];
        splitf(*(const float4*)p, *(const float4*)(p + 4), ahi[m * 2 + s], alo[m * 2 + s]);
      }
    // ctx B-frags: V[n = lgrp*8+q][e = wv*16+lrow]
    bf16x8 vbh, vbl;
    {
      float tv[8];
#pragma unroll
      for (int q = 0; q < 8; ++q) tv[q] = sV[(lgrp * 8 + q) * 68 + wv * 16 + lrow];
      splitf(make_float4(tv[0], tv[1], tv[2], tv[3]),
             make_float4(tv[4], tv[5], tv[6], tv[7]), vbh, vbl);
    }
    __syncthreads();   // B2: sK/sV reads drained; sDiag visible; kT writes may begin

#pragma unroll
    for (int t = 0; t < 4; ++t)
      ks[t] += dash_reg(t * 4 + wv, ahi, alo, pfh[t], pfl[t], sDiag, stab,
                        kThi, kTlo, lrow, lgrp);
    if (wv == 0)
      ks[4] += dash_reg(16, ahi, alo, pfh4, pfl4, sDiag, stab, kThi, kTlo, lrow, lgrp);
    __syncthreads();   // B3: full k' plane ready

#pragma unroll
    for (int jt = 0; jt < 17; ++jt) {
      bf16x8 ah = *(const bf16x8*)&kThi[(size_t)(jt * 16 + lrow) * KTS + lgrp * 8];
      bf16x8 al = *(const bf16x8*)&kTlo[(size_t)(jt * 16 + lrow) * KTS + lgrp * 8];
      acc[jt] = mfma3(ah, al, vbh, vbl, acc[jt]);
    }
    __syncthreads();   // B4: kT reads done before next stage overwrite
  }

  // ksum partials: reduce over lgrp (n-coverage), store per (jt, lrow)
  float* ksb = ksump + (size_t)(c8 * BH + bh) * MPAD;
#pragma unroll
  for (int t = 0; t < 4; ++t) {
    float s = ks[t];
    s += __shfl_xor(s, 16);
    s += __shfl_xor(s, 32);
    if (lgrp == 0) ksb[(t * 4 + wv) * 16 + lrow] = s;
  }
  if (wv == 0) {
    float s = ks[4];
    s += __shfl_xor(s, 16);
    s += __shfl_xor(s, 32);
    if (lgrp == 0) ksb[256 + lrow] = s;
  }
  // ctx slice: j = jt*16 + lgrp*4 + i, e = wv*16 + lrow
  float* cxb = ctxp + (size_t)(c8 * BH + bh) * MPAD * DDIM;
#pragma unroll
  for (int jt = 0; jt < 17; ++jt)
#pragma unroll
    for (int i = 0; i < 4; ++i)
      cxb[(size_t)(jt * 16 + lgrp * 4 + i) * DDIM + wv * 16 + lrow] = acc[jt][i];
}

// ---------------------------------------------------------------------------
// Reduce: ctx = sum_c8 ctxp[c8]; ksum = sum_c8 ksump[c8]
// ---------------------------------------------------------------------------
__global__ __launch_bounds__(256) void reduce_kernel(const float* __restrict__ ctxp,
                                                     const float* __restrict__ ksump,
                                                     float* __restrict__ ctx,
                                                     float* __restrict__ ksum) {
  const size_t SL = (size_t)BH * MPAD * DDIM;   // slice floats
  const int gid = blockIdx.x * 256 + threadIdx.x;
  if (gid < (int)(SL / 4)) {
    float4 s = make_float4(0.f, 0.f, 0.f, 0.f);
#pragma unroll
    for (int c = 0; c < 8; ++c) {
      float4 x = ((const float4*)ctxp)[c * (SL / 4) + gid];
      s.x += x.x; s.y += x.y; s.z += x.z; s.w += x.w;
    }
    ((float4*)ctx)[gid] = s;
  }
  if (gid < BH * MPAD) {
    float s = 0.f;
#pragma unroll
    for (int c = 0; c < 8; ++c) s += ksump[(size_t)c * BH * MPAD + gid];
    ksum[gid] = s;
  }
}

// ---------------------------------------------------------------------------
// Kernel C (all-MFMA): q_dash MFMA -> in-register max/exp/Dinv -> q'' bf16
// split qT in LDS -> GEMM2 MFMA. 64 rows/block. XCD-affinity decode keeps
// P + ctx[bh] (~140 KB) L2-resident per XCD.
// ---------------------------------------------------------------------------
__global__ __launch_bounds__(256, 2) void out_kernel(const float* __restrict__ q,
                                                     const short* __restrict__ phi,
                                                     const short* __restrict__ plo,
                                                     const float* __restrict__ ctx,
                                                     const float* __restrict__ ksum,
                                                     float* __restrict__ out) {
  __shared__ float buf[64 * 76];   // Q tile; reused as qT bf16 hi/lo [64][72]
  __shared__ float sCtx[64 * 68];
  __shared__ float sDiag[64];
  __shared__ float sKs[MPAD];
  unsigned short* qThi = (unsigned short*)buf;
  unsigned short* qTlo = qThi + 64 * 72;
  const int tid = threadIdx.x;
  const int lane = tid & 63, wv = tid >> 6, lrow = lane & 15, lgrp = lane >> 4;
  const int bh = blockIdx.x & 63, rc = blockIdx.x >> 6;   // XCD-affinity: xcd = bh%8
  const float* qb = q + ((size_t)bh * NSEQ + (size_t)rc * 64) * DDIM;

#pragma unroll
  for (int t = 0; t < 4; ++t) {
    int fid = tid + t * 256, r = fid >> 4, d4 = fid & 15;
    *(float4*)&buf[r * 76 + d4 * 4] = ((const float4*)qb)[fid];
  }
  for (int t = tid; t < MPAD; t += 256) sKs[t] = (t < MDIM) ? ksum[(size_t)bh * MPAD + t] : 0.f;
  __syncthreads();
  if (tid < 64) {
    float s = 0.f;
    const float* row = &buf[tid * 76];
#pragma unroll
    for (int d = 0; d < 64; d += 4) {
      float4 x = *(const float4*)(row + d);
      s = fmaf(x.x, x.x, fmaf(x.y, x.y, fmaf(x.z, x.z, fmaf(x.w, x.w, s))));
    }
    sDiag[tid] = s * DIAGF;
  }
  bf16x8 ahi[2], alo[2];
#pragma unroll
  for (int s = 0; s < 2; ++s) {
    const float* p = &buf[(wv * 16 + lrow) * 76 + s * 32 + lgrp * 8];
    splitf(*(const float4*)p, *(const float4*)(p + 4), ahi[s], alo[s]);
  }
  __syncthreads();   // sDiag ready, buf reads drained -> buf reusable

  f32x4 qd[17];
#pragma unroll
  for (int jt = 0; jt < 17; ++jt) {
    f32x4 a = {0.f, 0.f, 0.f, 0.f};
#pragma unroll
    for (int s = 0; s < 2; ++s) {
      const size_t bo = ((size_t)(jt * 16 + lrow)) * DDIM + s * 32 + lgrp * 8;
      a = mfma3(ahi[s], alo[s], *(const bf16x8*)(phi + bo), *(const bf16x8*)(plo + bo), a);
    }
#pragma unroll
    for (int i = 0; i < 4; ++i) qd[jt][i] = a[i] * NORMF;
  }

  // rows wv*16 + lgrp*4 + i; 16 lanes (lrow) share each row set
  float di[4];
#pragma unroll
  for (int i = 0; i < 4; ++i) {
    float m = -1e30f;
#pragma unroll
    for (int jt = 0; jt < 17; ++jt)
      if (jt < 16 || lrow < 10) m = fmaxf(m, qd[jt][i]);
    m = fmaxf(m, __shfl_xor(m, 1));
    m = fmaxf(m, __shfl_xor(m, 2));
    m = fmaxf(m, __shfl_xor(m, 4));
    m = fmaxf(m, __shfl_xor(m, 8));
    const float dg = sDiag[wv * 16 + lgrp * 4 + i];
    float s = 0.f;
#pragma unroll
    for (int jt = 0; jt < 17; ++jt) {
      const int jg = jt * 16 + lrow;
      float val = (jg < MDIM) ? RATIO * (__expf(qd[jt][i] - dg - m) + EPSF) : 0.f;
      qd[jt][i] = val;
      s = fmaf(val, sKs[jg], s);
    }
    s += __shfl_xor(s, 1);
    s += __shfl_xor(s, 2);
    s += __shfl_xor(s, 4);
    s += __shfl_xor(s, 8);
    di[i] = 1.0f / s;
  }

  f32x4 accO[4];
#pragma unroll
  for (int mt = 0; mt < 4; ++mt) accO[mt] = (f32x4){0.f, 0.f, 0.f, 0.f};

#pragma unroll
  for (int c = 0; c < 5; ++c) {
    const int nwr = (c < 4) ? 4 : 2;   // chunk 4: t=1 zero-fill (mask stale LDS)
    const int nks = (c < 4) ? 2 : 1;
    const int jn = (c < 4) ? 64 : 10;
#pragma unroll
    for (int t = 0; t < nwr; ++t) {
      const int jt = c * 4 + t;
#pragma unroll
      for (int i = 0; i < 4; ++i) {
        unsigned short h = 0, l = 0;
        if (jt < 17) split1(qd[jt][i] * di[i], h, l);
        qThi[(wv * 16 + lgrp * 4 + i) * 72 + t * 16 + lrow] = h;
        qTlo[(wv * 16 + lgrp * 4 + i) * 72 + t * 16 + lrow] = l;
      }
    }
#pragma unroll
    for (int t = 0; t < 4; ++t) {
      int fid = tid + t * 256, r = fid >> 4, e4 = fid & 15;
      if (r < jn)
        *(float4*)&sCtx[r * 68 + e4 * 4] =
            ((const float4*)(ctx + ((size_t)bh * MPAD + c * 64 + r) * DDIM))[e4];
    }
    __syncthreads();   // qT chunk + sCtx chunk ready
#pragma unroll
    for (int ks2 = 0; ks2 < nks; ++ks2) {
      float tv[8];
#pragma unroll
      for (int e = 0; e < 8; ++e)
        tv[e] = sCtx[(ks2 * 32 + lgrp * 8 + e) * 68 + wv * 16 + lrow];
      bf16x8 cbh, cbl;
      splitf(make_float4(tv[0], tv[1], tv[2], tv[3]),
             make_float4(tv[4], tv[5], tv[6], tv[7]), cbh, cbl);
#pragma unroll
      for (int mt = 0; mt < 4; ++mt) {
        bf16x8 ah = *(const bf16x8*)&qThi[(mt * 16 + lrow) * 72 + ks2 * 32 + lgrp * 8];
        bf16x8 al = *(const bf16x8*)&qTlo[(mt * 16 + lrow) * 72 + ks2 * 32 + lgrp * 8];
        accO[mt] = mfma3(ah, al, cbh, cbl, accO[mt]);
      }
    }
    __syncthreads();   // reads done before next chunk overwrites
  }

#pragma unroll
  for (int mt = 0; mt < 4; ++mt) {
#pragma unroll
    for (int i = 0; i < 4; ++i) {
      const int r = mt * 16 + lgrp * 4 + i;
      out[((size_t)bh * NSEQ + (size_t)rc * 64 + r) * DDIM + wv * 16 + lrow] = accO[mt][i];
    }
  }
}

extern "C" void kernel_launch(void* const* d_in, const int* in_sizes, int n_in,
                              void* d_out, int out_size, void* d_ws, size_t ws_size,
                              hipStream_t stream) {
  (void)in_sizes; (void)n_in; (void)out_size; (void)ws_size;
  const float* q = (const float*)d_in[0];
  const float* k = (const float*)d_in[1];
  const float* v = (const float*)d_in[2];
  const float* proj = (const float*)d_in[3];
  float* out = (float*)d_out;

  // d_ws layout: kmax | ctx | ksum | phi | plo   (~4.6 MB)
  unsigned* kmax = (unsigned*)d_ws;
  float* ctx = (float*)((char*)d_ws + 256);
  float* ksum = ctx + (size_t)BH * MPAD * DDIM;
  short* phi = (short*)(ksum + (size_t)BH * MPAD);
  short* plo = phi + (size_t)MPAD * DDIM;

  // d_out used as scratch for the 8 ctx/ksum slices (36.2 MB < 67 MB);
  // out_kernel fully overwrites d_out afterwards.
  const size_t SL = (size_t)BH * MPAD * DDIM;
  float* ctxp = (float*)d_out;
  float* ksump = ctxp + 8 * SL;

  hipMemsetAsync(d_ws, 0, 256, stream);   // kmax only
  pprep_kernel<<<dim3((MPAD * DDIM + 255) / 256), dim3(256), 0, stream>>>(proj, phi, plo);
  kmax_kernel<<<dim3(512), dim3(256), 0, stream>>>(k, phi, plo, kmax);
  ctx_kernel<<<dim3(BH * 8), dim3(256), 0, stream>>>(k, v, phi, plo, kmax, ctxp, ksump);
  reduce_kernel<<<dim3((unsigned)(SL / 4 / 256)), dim3(256), 0, stream>>>(ctxp, ksump, ctx, ksum);
  out_kernel<<<dim3(BH * 64), dim3(256), 0, stream>>>(q, phi, plo, ctx, ksum, out);
}

// Round 8
// 303.901 us; speedup vs baseline: 1.6951x; 1.0701x over previous
//
#include <hip/hip_runtime.h>
#include <math.h>

#define BH    64
#define NSEQ  4096
#define DDIM  64
#define MDIM  266
#define MPAD  272
#define KTS   40                     // ctx-kernel kT row stride in ushorts
#define QTS   296                    // out-kernel qT row stride in ushorts
#define RATIO 0.06131393394849658f   // 1/sqrt(266)
#define NORMF 0.35355339059327373f   // 64^-0.25
#define DIAGF 0.0625f                // 0.5 * 64^-0.5
#define EPSF  1e-4f

typedef __attribute__((ext_vector_type(8))) short bf16x8;
typedef __attribute__((ext_vector_type(4))) float f32x4;

__device__ __forceinline__ unsigned fenc(float f) {
  unsigned u = __float_as_uint(f);
  return (u & 0x80000000u) ? ~u : (u | 0x80000000u);
}
__device__ __forceinline__ float fdec(unsigned u) {
  return (u & 0x80000000u) ? __uint_as_float(u & 0x7fffffffu) : __uint_as_float(~u);
}

__device__ __forceinline__ void split1(float x, unsigned short& h, unsigned short& l) {
  unsigned ux = __float_as_uint(x);
  float hf = __uint_as_float(ux & 0xffff0000u);
  h = (unsigned short)(ux >> 16);
  l = (unsigned short)(__float_as_uint(x - hf) >> 16);
}

__device__ __forceinline__ void splitf(float4 a, float4 b, bf16x8& hi, bf16x8& lo) {
  float x[8] = {a.x, a.y, a.z, a.w, b.x, b.y, b.z, b.w};
#pragma unroll
  for (int e = 0; e < 8; ++e) {
    unsigned short h, l;
    split1(x[e], h, l);
    hi[e] = (short)h;
    lo[e] = (short)l;
  }
}

// split-precision GEMM accumulate: acc += hh + hl + lh  (ll term ~2^-16, dropped)
__device__ __forceinline__ f32x4 mfma3(bf16x8 ah, bf16x8 al, bf16x8 bh, bf16x8 bl, f32x4 acc) {
  acc = __builtin_amdgcn_mfma_f32_16x16x32_bf16(ah, bh, acc, 0, 0, 0);
  acc = __builtin_amdgcn_mfma_f32_16x16x32_bf16(ah, bl, acc, 0, 0, 0);
  acc = __builtin_amdgcn_mfma_f32_16x16x32_bf16(al, bh, acc, 0, 0, 0);
  return acc;
}

// ---------------------------------------------------------------------------
// P prep: proj [266][64] f32 -> phi/plo [272][64] bf16 planes (rows >=266 zero)
// ---------------------------------------------------------------------------
__global__ __launch_bounds__(256) void pprep_kernel(const float* __restrict__ proj,
                                                    short* __restrict__ phi,
                                                    short* __restrict__ plo) {
  int idx = blockIdx.x * 256 + threadIdx.x;
  if (idx >= MPAD * DDIM) return;
  int j = idx >> 6;
  float x = (j < MDIM) ? proj[idx] : 0.f;
  unsigned short h, l;
  split1(x, h, l);
  phi[idx] = (short)h;
  plo[idx] = (short)l;
}

// ---------------------------------------------------------------------------
// Kernel A: global max of k_dash = NORMF*(K.P^T), MFMA bf16x3.
// 512 blocks x 8 chunks of 64 rows; one atomic per block.
// ---------------------------------------------------------------------------
__global__ __launch_bounds__(256) void kmax_kernel(const float* __restrict__ k,
                                                   const short* __restrict__ phi,
                                                   const short* __restrict__ plo,
                                                   unsigned* __restrict__ kmax) {
  __shared__ float sK[64 * 76];
  __shared__ float wmax[4];
  const int tid = threadIdx.x;
  const int lane = tid & 63, wv = tid >> 6, lrow = lane & 15, lgrp = lane >> 4;

  float tmax = -1e30f;
  for (int it = 0; it < 8; ++it) {
    const int chunk = blockIdx.x * 8 + it;   // 0..4095
    const int bh = chunk >> 6, ch = chunk & 63;
    const float* kb = k + ((size_t)bh * NSEQ + (size_t)ch * 64) * DDIM;
    __syncthreads();
#pragma unroll
    for (int t = 0; t < 4; ++t) {
      int fid = tid + t * 256, r = fid >> 4, d4 = fid & 15;
      *(float4*)&sK[r * 76 + d4 * 4] = ((const float4*)kb)[fid];
    }
    __syncthreads();

    bf16x8 ahi[2], alo[2];
#pragma unroll
    for (int s = 0; s < 2; ++s) {
      const float* p = &sK[(wv * 16 + lrow) * 76 + s * 32 + lgrp * 8];
      splitf(*(const float4*)p, *(const float4*)(p + 4), ahi[s], alo[s]);
    }

#pragma unroll
    for (int jt = 0; jt < 17; ++jt) {
      f32x4 acc = {0.f, 0.f, 0.f, 0.f};
#pragma unroll
      for (int s = 0; s < 2; ++s) {
        const size_t bo = ((size_t)(jt * 16 + lrow)) * DDIM + s * 32 + lgrp * 8;
        acc = mfma3(ahi[s], alo[s], *(const bf16x8*)(phi + bo), *(const bf16x8*)(plo + bo), acc);
      }
      if (jt < 16 || lrow < 10) {
#pragma unroll
        for (int i = 0; i < 4; ++i) tmax = fmaxf(tmax, acc[i]);
      }
    }
  }
#pragma unroll
  for (int off = 32; off; off >>= 1) tmax = fmaxf(tmax, __shfl_xor(tmax, off));
  if (lane == 0) wmax[wv] = tmax;
  __syncthreads();
  if (tid == 0) {
    float m = fmaxf(fmaxf(wmax[0], wmax[1]), fmaxf(wmax[2], wmax[3]));
    atomicMax(kmax, fenc(m * NORMF));
  }
}

// dash helper, P-fragments from REGISTERS (rt-invariant, hoisted)
__device__ __forceinline__ float dash_reg(int jt, const bf16x8* ahi, const bf16x8* alo,
                                          const bf16x8* ph, const bf16x8* pl,
                                          const float* sDiag, float stab,
                                          unsigned short* kThi, unsigned short* kTlo,
                                          int lrow, int lgrp) {
  float kssum = 0.f;
  const int jg = jt * 16 + lrow;
#pragma unroll
  for (int m = 0; m < 2; ++m) {
    f32x4 d = {0.f, 0.f, 0.f, 0.f};
#pragma unroll
    for (int s = 0; s < 2; ++s)
      d = mfma3(ahi[m * 2 + s], alo[m * 2 + s], ph[s], pl[s], d);
    ushort4 h4, l4;
#pragma unroll
    for (int i = 0; i < 4; ++i) {
      const int nl = m * 16 + lgrp * 4 + i;
      float kd = d[i] * NORMF;
      float kp = (jg < MDIM) ? RATIO * (__expf(kd - sDiag[nl] - stab) + EPSF) : 0.f;
      kssum += kp;
      unsigned short h, l;
      split1(kp, h, l);
      ((unsigned short*)&h4)[i] = h;
      ((unsigned short*)&l4)[i] = l;
    }
    *(ushort4*)&kThi[(size_t)jg * KTS + m * 16 + lgrp * 4] = h4;
    *(ushort4*)&kTlo[(size_t)jg * KTS + m * 16 + lgrp * 4] = l4;
  }
  return kssum;
}

// ---------------------------------------------------------------------------
// Kernel B (unchanged from R7): P-frags hoisted; 32-row tiles; no atomics.
// ---------------------------------------------------------------------------
__global__ __launch_bounds__(256, 2) void ctx_kernel(const float* __restrict__ k,
                                                     const float* __restrict__ v,
                                                     const short* __restrict__ phi,
                                                     const short* __restrict__ plo,
                                                     const unsigned* __restrict__ kmaxp,
                                                     float* __restrict__ ctxp,
                                                     float* __restrict__ ksump) {
  __shared__ unsigned short kThi[MPAD * KTS];
  __shared__ unsigned short kTlo[MPAD * KTS];
  __shared__ float sV[32 * 68];
  __shared__ float sDiag[32];
  float* sK = (float*)kThi;   // staging overlay, stride 76, 32 rows

  const int tid = threadIdx.x;
  const int lane = tid & 63, wv = tid >> 6, lrow = lane & 15, lgrp = lane >> 4;
  const int bh = blockIdx.x & 63, c8 = blockIdx.x >> 6;   // XCD-affinity: xcd = bh%8
  const float stab = fdec(*kmaxp);
  const float* kb = k + ((size_t)bh * NSEQ + (size_t)c8 * 512) * DDIM;
  const float* vb = v + ((size_t)bh * NSEQ + (size_t)c8 * 512) * DDIM;

  bf16x8 pfh[4][2], pfl[4][2];
#pragma unroll
  for (int t = 0; t < 4; ++t)
#pragma unroll
    for (int s = 0; s < 2; ++s) {
      const size_t bo = ((size_t)((t * 4 + wv) * 16 + lrow)) * DDIM + s * 32 + lgrp * 8;
      pfh[t][s] = *(const bf16x8*)(phi + bo);
      pfl[t][s] = *(const bf16x8*)(plo + bo);
    }
  bf16x8 pfh4[2], pfl4[2];
  if (wv == 0) {
#pragma unroll
    for (int s = 0; s < 2; ++s) {
      const size_t bo = ((size_t)(256 + lrow)) * DDIM + s * 32 + lgrp * 8;
      pfh4[s] = *(const bf16x8*)(phi + bo);
      pfl4[s] = *(const bf16x8*)(plo + bo);
    }
  }

  f32x4 acc[17];
#pragma unroll
  for (int jt = 0; jt < 17; ++jt) acc[jt] = (f32x4){0.f, 0.f, 0.f, 0.f};
  float ks[5] = {0.f, 0.f, 0.f, 0.f, 0.f};

  for (int rt = 0; rt < 16; ++rt) {
#pragma unroll
    for (int t = 0; t < 2; ++t) {
      int fid = tid + t * 256, r = fid >> 4, d4 = fid & 15;
      *(float4*)&sK[r * 76 + d4 * 4] = ((const float4*)(kb + (size_t)rt * 32 * DDIM))[fid];
      *(float4*)&sV[r * 68 + d4 * 4] = ((const float4*)(vb + (size_t)rt * 32 * DDIM))[fid];
    }
    __syncthreads();   // B1
    if (tid < 32) {
      float s = 0.f;
      const float* row = &sK[tid * 76];
#pragma unroll
      for (int d = 0; d < 64; d += 4) {
        float4 x = *(const float4*)(row + d);
        s = fmaf(x.x, x.x, fmaf(x.y, x.y, fmaf(x.z, x.z, fmaf(x.w, x.w, s))));
      }
      sDiag[tid] = s * DIAGF;
    }
    bf16x8 ahi[4], alo[4];
#pragma unroll
    for (int m = 0; m < 2; ++m)
#pragma unroll
      for (int s = 0; s < 2; ++s) {
        const float* p = &sK[(m * 16 + lrow) * 76 + s * 32 + lgrp * 8];
        splitf(*(const float4*)p, *(const float4*)(p + 4), ahi[m * 2 + s], alo[m * 2 + s]);
      }
    bf16x8 vbh, vbl;
    {
      float tv[8];
#pragma unroll
      for (int q = 0; q < 8; ++q) tv[q] = sV[(lgrp * 8 + q) * 68 + wv * 16 + lrow];
      splitf(make_float4(tv[0], tv[1], tv[2], tv[3]),
             make_float4(tv[4], tv[5], tv[6], tv[7]), vbh, vbl);
    }
    __syncthreads();   // B2

#pragma unroll
    for (int t = 0; t < 4; ++t)
      ks[t] += dash_reg(t * 4 + wv, ahi, alo, pfh[t], pfl[t], sDiag, stab,
                        kThi, kTlo, lrow, lgrp);
    if (wv == 0)
      ks[4] += dash_reg(16, ahi, alo, pfh4, pfl4, sDiag, stab, kThi, kTlo, lrow, lgrp);
    __syncthreads();   // B3

#pragma unroll
    for (int jt = 0; jt < 17; ++jt) {
      bf16x8 ah = *(const bf16x8*)&kThi[(size_t)(jt * 16 + lrow) * KTS + lgrp * 8];
      bf16x8 al = *(const bf16x8*)&kTlo[(size_t)(jt * 16 + lrow) * KTS + lgrp * 8];
      acc[jt] = mfma3(ah, al, vbh, vbl, acc[jt]);
    }
    __syncthreads();   // B4
  }

  float* ksb = ksump + (size_t)(c8 * BH + bh) * MPAD;
#pragma unroll
  for (int t = 0; t < 4; ++t) {
    float s = ks[t];
    s += __shfl_xor(s, 16);
    s += __shfl_xor(s, 32);
    if (lgrp == 0) ksb[(t * 4 + wv) * 16 + lrow] = s;
  }
  if (wv == 0) {
    float s = ks[4];
    s += __shfl_xor(s, 16);
    s += __shfl_xor(s, 32);
    if (lgrp == 0) ksb[256 + lrow] = s;
  }
  float* cxb = ctxp + (size_t)(c8 * BH + bh) * MPAD * DDIM;
#pragma unroll
  for (int jt = 0; jt < 17; ++jt)
#pragma unroll
    for (int i = 0; i < 4; ++i)
      cxb[(size_t)(jt * 16 + lgrp * 4 + i) * DDIM + wv * 16 + lrow] = acc[jt][i];
}

// ---------------------------------------------------------------------------
// Reduce: ctx = sum_c8 ctxp[c8]; ksum = sum_c8 ksump[c8]
// ---------------------------------------------------------------------------
__global__ __launch_bounds__(256) void reduce_kernel(const float* __restrict__ ctxp,
                                                     const float* __restrict__ ksump,
                                                     float* __restrict__ ctx,
                                                     float* __restrict__ ksum) {
  const size_t SL = (size_t)BH * MPAD * DDIM;
  const int gid = blockIdx.x * 256 + threadIdx.x;
  if (gid < (int)(SL / 4)) {
    float4 s = make_float4(0.f, 0.f, 0.f, 0.f);
#pragma unroll
    for (int c = 0; c < 8; ++c) {
      float4 x = ((const float4*)ctxp)[c * (SL / 4) + gid];
      s.x += x.x; s.y += x.y; s.z += x.z; s.w += x.w;
    }
    ((float4*)ctx)[gid] = s;
  }
  if (gid < BH * MPAD) {
    float s = 0.f;
#pragma unroll
    for (int c = 0; c < 8; ++c) s += ksump[(size_t)c * BH * MPAD + gid];
    ksum[gid] = s;
  }
}

// ---------------------------------------------------------------------------
// Kernel C v2 (ctx-shaped): 512 blocks x 512 rows, rt-loop of 32-row tiles.
// ctx B-frags hoisted to registers once per block (9 ksteps x hi/lo).
// Per rt: stage Q -> dash (waves split 17 jt, P from L2 once) -> cross-wave
// max/Dinv via small LDS -> qT bf16-split -> GEMM2 from LDS+regs -> store.
// ---------------------------------------------------------------------------
__global__ __launch_bounds__(256, 2) void out_kernel(const float* __restrict__ q,
                                                     const short* __restrict__ phi,
                                                     const short* __restrict__ plo,
                                                     const float* __restrict__ ctx,
                                                     const float* __restrict__ ksum,
                                                     float* __restrict__ out) {
  __shared__ unsigned short qThi[32 * QTS];   // 18.9 KB
  __shared__ unsigned short qTlo[32 * QTS];   // 18.9 KB
  __shared__ float sQ[32 * 76];               // 9.7 KB
  __shared__ float sKs[MPAD];
  __shared__ float sDiag[32];
  __shared__ float sMax[4 * 32];
  __shared__ float sSum[4 * 32];
  const int tid = threadIdx.x;
  const int lane = tid & 63, wv = tid >> 6, lrow = lane & 15, lgrp = lane >> 4;
  const int bh = blockIdx.x & 63, c8 = blockIdx.x >> 6;   // XCD-affinity: xcd = bh%8
  const float* qb = q + ((size_t)bh * NSEQ + (size_t)c8 * 512) * DDIM;

  // zero qT pad cols 272..287 once (read by kst=8 with B=0 there; avoid NaN*0)
  for (int idx = tid; idx < 512; idx += 256) {
    const int r = idx >> 4, cc = 272 + (idx & 15);
    qThi[r * QTS + cc] = 0;
    qTlo[r * QTS + cc] = 0;
  }
  for (int t = tid; t < MPAD; t += 256) sKs[t] = ksum[(size_t)bh * MPAD + t];

  // hoist ctx B-frags: e = wv*16+lrow fixed, k = j = kst*32 + lgrp*8 + qq
  bf16x8 cbh[9], cbl[9];
#pragma unroll
  for (int kst = 0; kst < 9; ++kst) {
    float tv[8];
#pragma unroll
    for (int qq = 0; qq < 8; ++qq) {
      const int j = kst * 32 + lgrp * 8 + qq;
      tv[qq] = (j < MPAD) ? ctx[((size_t)bh * MPAD + j) * DDIM + wv * 16 + lrow] : 0.f;
    }
    splitf(make_float4(tv[0], tv[1], tv[2], tv[3]),
           make_float4(tv[4], tv[5], tv[6], tv[7]), cbh[kst], cbl[kst]);
  }

  for (int rt = 0; rt < 16; ++rt) {
    __syncthreads();   // B0: prev GEMM2 qT reads done; init writes visible (rt=0)
#pragma unroll
    for (int t = 0; t < 2; ++t) {
      int fid = tid + t * 256, r = fid >> 4, d4 = fid & 15;
      *(float4*)&sQ[r * 76 + d4 * 4] = ((const float4*)(qb + (size_t)rt * 32 * DDIM))[fid];
    }
    __syncthreads();   // B1: staging visible
    if (tid < 32) {
      float s = 0.f;
      const float* row = &sQ[tid * 76];
#pragma unroll
      for (int d = 0; d < 64; d += 4) {
        float4 x = *(const float4*)(row + d);
        s = fmaf(x.x, x.x, fmaf(x.y, x.y, fmaf(x.z, x.z, fmaf(x.w, x.w, s))));
      }
      sDiag[tid] = s * DIAGF;
    }
    bf16x8 ahi[4], alo[4];   // [m*2+s]
#pragma unroll
    for (int m = 0; m < 2; ++m)
#pragma unroll
      for (int s = 0; s < 2; ++s) {
        const float* p = &sQ[(m * 16 + lrow) * 76 + s * 32 + lgrp * 8];
        splitf(*(const float4*)p, *(const float4*)(p + 4), ahi[m * 2 + s], alo[m * 2 + s]);
      }
    __syncthreads();   // B2: sQ reads drained; sDiag visible

    // dash: wave wv owns jt {wv, 4+wv, 8+wv, 12+wv} (+16 for wv0)
    f32x4 qd[4][2];
    f32x4 qd4[2] = {(f32x4){0.f, 0.f, 0.f, 0.f}, (f32x4){0.f, 0.f, 0.f, 0.f}};
#pragma unroll
    for (int t = 0; t < 4; ++t) {
      const int jt = t * 4 + wv;
      const size_t bo = ((size_t)(jt * 16 + lrow)) * DDIM + lgrp * 8;
      bf16x8 ph0 = *(const bf16x8*)(phi + bo);
      bf16x8 pl0 = *(const bf16x8*)(plo + bo);
      bf16x8 ph1 = *(const bf16x8*)(phi + bo + 32);
      bf16x8 pl1 = *(const bf16x8*)(plo + bo + 32);
#pragma unroll
      for (int m = 0; m < 2; ++m) {
        f32x4 d = {0.f, 0.f, 0.f, 0.f};
        d = mfma3(ahi[m * 2 + 0], alo[m * 2 + 0], ph0, pl0, d);
        d = mfma3(ahi[m * 2 + 1], alo[m * 2 + 1], ph1, pl1, d);
        qd[t][m] = d * NORMF;
      }
    }
    if (wv == 0) {
      const size_t bo = ((size_t)(256 + lrow)) * DDIM + lgrp * 8;
      bf16x8 ph0 = *(const bf16x8*)(phi + bo);
      bf16x8 pl0 = *(const bf16x8*)(plo + bo);
      bf16x8 ph1 = *(const bf16x8*)(phi + bo + 32);
      bf16x8 pl1 = *(const bf16x8*)(plo + bo + 32);
#pragma unroll
      for (int m = 0; m < 2; ++m) {
        f32x4 d = {0.f, 0.f, 0.f, 0.f};
        d = mfma3(ahi[m * 2 + 0], alo[m * 2 + 0], ph0, pl0, d);
        d = mfma3(ahi[m * 2 + 1], alo[m * 2 + 1], ph1, pl1, d);
        qd4[m] = d * NORMF;
      }
    }

    // per-row max: lane-local over jts, shfl over lrow, cross-wave via LDS
#pragma unroll
    for (int m = 0; m < 2; ++m)
#pragma unroll
      for (int i = 0; i < 4; ++i) {
        float mx = fmaxf(fmaxf(qd[0][m][i], qd[1][m][i]), fmaxf(qd[2][m][i], qd[3][m][i]));
        if (wv == 0 && lrow < 10) mx = fmaxf(mx, qd4[m][i]);
        mx = fmaxf(mx, __shfl_xor(mx, 1));
        mx = fmaxf(mx, __shfl_xor(mx, 2));
        mx = fmaxf(mx, __shfl_xor(mx, 4));
        mx = fmaxf(mx, __shfl_xor(mx, 8));
        if (lrow == 0) sMax[wv * 32 + m * 16 + lgrp * 4 + i] = mx;
      }
    __syncthreads();   // B3: max partials visible

    float mrow[2][4], dgr[2][4], srow[2][4];
#pragma unroll
    for (int m = 0; m < 2; ++m)
#pragma unroll
      for (int i = 0; i < 4; ++i) {
        const int row = m * 16 + lgrp * 4 + i;
        mrow[m][i] = fmaxf(fmaxf(sMax[row], sMax[32 + row]),
                           fmaxf(sMax[64 + row], sMax[96 + row]));
        dgr[m][i] = sDiag[row];
        srow[m][i] = 0.f;
      }
#pragma unroll
    for (int t = 0; t < 4; ++t) {
      const int jg = (t * 4 + wv) * 16 + lrow;   // <= 255, always < MDIM
      const float ksj = sKs[jg];
#pragma unroll
      for (int m = 0; m < 2; ++m)
#pragma unroll
        for (int i = 0; i < 4; ++i) {
          float val = RATIO * (__expf(qd[t][m][i] - dgr[m][i] - mrow[m][i]) + EPSF);
          qd[t][m][i] = val;
          srow[m][i] = fmaf(val, ksj, srow[m][i]);
        }
    }
    if (wv == 0) {
      const int jg = 256 + lrow;
      const float ksj = sKs[jg];
#pragma unroll
      for (int m = 0; m < 2; ++m)
#pragma unroll
        for (int i = 0; i < 4; ++i) {
          float val = (jg < MDIM) ? RATIO * (__expf(qd4[m][i] - dgr[m][i] - mrow[m][i]) + EPSF)
                                  : 0.f;
          qd4[m][i] = val;
          srow[m][i] = fmaf(val, ksj, srow[m][i]);
        }
    }
#pragma unroll
    for (int m = 0; m < 2; ++m)
#pragma unroll
      for (int i = 0; i < 4; ++i) {
        float s = srow[m][i];
        s += __shfl_xor(s, 1);
        s += __shfl_xor(s, 2);
        s += __shfl_xor(s, 4);
        s += __shfl_xor(s, 8);
        if (lrow == 0) sSum[wv * 32 + m * 16 + lgrp * 4 + i] = s;
      }
    __syncthreads();   // B4: sum partials visible

    float di[2][4];
#pragma unroll
    for (int m = 0; m < 2; ++m)
#pragma unroll
      for (int i = 0; i < 4; ++i) {
        const int row = m * 16 + lgrp * 4 + i;
        di[m][i] = 1.0f / (sSum[row] + sSum[32 + row] + sSum[64 + row] + sSum[96 + row]);
      }

    // write q''*Dinv to qT (bf16 split), transposed [n][j]
#pragma unroll
    for (int t = 0; t < 4; ++t) {
      const int j = (t * 4 + wv) * 16 + lrow;
#pragma unroll
      for (int m = 0; m < 2; ++m)
#pragma unroll
        for (int i = 0; i < 4; ++i) {
          unsigned short h, l;
          split1(qd[t][m][i] * di[m][i], h, l);
          const int n = m * 16 + lgrp * 4 + i;
          qThi[n * QTS + j] = h;
          qTlo[n * QTS + j] = l;
        }
    }
    if (wv == 0) {
      const int j = 256 + lrow;
#pragma unroll
      for (int m = 0; m < 2; ++m)
#pragma unroll
        for (int i = 0; i < 4; ++i) {
          unsigned short h, l;
          split1(qd4[m][i] * di[m][i], h, l);
          const int n = m * 16 + lgrp * 4 + i;
          qThi[n * QTS + j] = h;
          qTlo[n * QTS + j] = l;
        }
    }
    __syncthreads();   // B5: qT ready

    // GEMM2: out[n,e] = sum_j q''[n,j] * ctx[j,e]; B-frags in registers
#pragma unroll
    for (int mt = 0; mt < 2; ++mt) {
      f32x4 acc = {0.f, 0.f, 0.f, 0.f};
#pragma unroll
      for (int kst = 0; kst < 9; ++kst) {
        bf16x8 ah = *(const bf16x8*)&qThi[(mt * 16 + lrow) * QTS + kst * 32 + lgrp * 8];
        bf16x8 al = *(const bf16x8*)&qTlo[(mt * 16 + lrow) * QTS + kst * 32 + lgrp * 8];
        acc = mfma3(ah, al, cbh[kst], cbl[kst], acc);
      }
#pragma unroll
      for (int i = 0; i < 4; ++i) {
        const int n = rt * 32 + mt * 16 + lgrp * 4 + i;
        out[((size_t)bh * NSEQ + (size_t)c8 * 512 + n) * DDIM + wv * 16 + lrow] = acc[i];
      }
    }
  }
}

extern "C" void kernel_launch(void* const* d_in, const int* in_sizes, int n_in,
                              void* d_out, int out_size, void* d_ws, size_t ws_size,
                              hipStream_t stream) {
  (void)in_sizes; (void)n_in; (void)out_size; (void)ws_size;
  const float* q = (const float*)d_in[0];
  const float* k = (const float*)d_in[1];
  const float* v = (const float*)d_in[2];
  const float* proj = (const float*)d_in[3];
  float* out = (float*)d_out;

  // d_ws layout: kmax | ctx | ksum | phi | plo   (~4.6 MB)
  unsigned* kmax = (unsigned*)d_ws;
  float* ctx = (float*)((char*)d_ws + 256);
  float* ksum = ctx + (size_t)BH * MPAD * DDIM;
  short* phi = (short*)(ksum + (size_t)BH * MPAD);
  short* plo = phi + (size_t)MPAD * DDIM;

  // d_out used as scratch for the 8 ctx/ksum slices (36 MB < 67 MB);
  // out_kernel fully overwrites d_out afterwards.
  const size_t SL = (size_t)BH * MPAD * DDIM;
  float* ctxp = (float*)d_out;
  float* ksump = ctxp + 8 * SL;

  hipMemsetAsync(d_ws, 0, 256, stream);   // kmax only
  pprep_kernel<<<dim3((MPAD * DDIM + 255) / 256), dim3(256), 0, stream>>>(proj, phi, plo);
  kmax_kernel<<<dim3(512), dim3(256), 0, stream>>>(k, phi, plo, kmax);
  ctx_kernel<<<dim3(BH * 8), dim3(256), 0, stream>>>(k, v, phi, plo, kmax, ctxp, ksump);
  reduce_kernel<<<dim3((unsigned)(SL / 4 / 256)), dim3(256), 0, stream>>>(ctxp, ksump, ctx, ksum);
  out_kernel<<<dim3(BH * 8), dim3(256), 0, stream>>>(q, phi, plo, ctx, ksum, out);
}